// Round 1
// baseline (161.772 us; speedup 1.0000x reference)
//
#include <hip/hip_runtime.h>

#define SEQ 512
#define HID 768
#define P2  46
#define NTP 48      // padded N (3 x 16)
#define MT  64      // rows per block
#define KC  64      // K chunk
#define BLK 256
#define NCHUNK (HID / KC)   // 12

typedef short bf16x8 __attribute__((ext_vector_type(8)));
typedef float f32x4  __attribute__((ext_vector_type(4)));

__device__ __forceinline__ unsigned short f2bf(float f) {
  union { float f; unsigned int u; } v; v.f = f;
  return (unsigned short)((v.u + 0x7FFFu + ((v.u >> 16) & 1u)) >> 16);
}

// q[b][p] = (h[b,i0,:] + h[b,i1,:]) . W[p,:]   (exact fp32)
__global__ __launch_bounds__(64) void qk_kernel(const float* __restrict__ h,
                                                const int* __restrict__ ids,
                                                const float* __restrict__ W,
                                                float* __restrict__ q) {
  int b = blockIdx.x, p = blockIdx.y;      // p in [0,46)
  int lane = threadIdx.x;
  int i0 = ids[b * 2 + 0], i1 = ids[b * 2 + 1];
  const float* r0 = h + ((size_t)b * SEQ + i0) * HID;
  const float* r1 = h + ((size_t)b * SEQ + i1) * HID;
  const float* w  = W + (size_t)p * HID;
  float acc = 0.f;
  #pragma unroll
  for (int j = 0; j < HID / 64; ++j) {
    int k = lane + j * 64;
    acc += (r0[k] + r1[k]) * w[k];
  }
  #pragma unroll
  for (int off = 32; off > 0; off >>= 1)
    acc += __shfl_down(acc, off, 64);
  if (lane == 0) q[b * P2 + p] = acc;
}

__global__ __launch_bounds__(BLK) void gemm_kernel(const float* __restrict__ h,
                                                   const int* __restrict__ mask,
                                                   const float* __restrict__ W,
                                                   const float* __restrict__ bias,
                                                   const float* __restrict__ q,
                                                   float* __restrict__ out) {
  // LDS: bf16 tiles, inner dim padded 64 -> 72 (row stride 144 B -> 2-way bank alias, free)
  __shared__ __align__(16) unsigned short hA[2][MT][72];
  __shared__ __align__(16) unsigned short wB[2][NTP][72];

  const int tid  = threadIdx.x;
  const int row0 = blockIdx.x * MT;      // flat row = b*SEQ + s
  const int b    = row0 >> 9;            // SEQ = 512
  const int lane = tid & 63, wv = tid >> 6;
  const int mr = lane & 15, qd = lane >> 4;

  float4 hreg[4];
  float4 wreg[3];

  auto loadH = [&](int c) {
    int k0 = c * KC;
    #pragma unroll
    for (int i = 0; i < 4; ++i) {
      int idx = tid + i * BLK;           // 0..1023
      int r = idx >> 4, c4 = idx & 15;
      hreg[i] = *(const float4*)(h + ((size_t)(row0 + r)) * HID + k0 + c4 * 4);
    }
  };
  auto loadW = [&](int c) {
    int k0 = c * KC;
    #pragma unroll
    for (int i = 0; i < 3; ++i) {
      int idx = tid + i * BLK;           // 0..767
      int r = idx >> 4, c4 = idx & 15;
      if (r < P2)
        wreg[i] = *(const float4*)(W + (size_t)r * HID + k0 + c4 * 4);
      else
        wreg[i] = make_float4(0.f, 0.f, 0.f, 0.f);
    }
  };
  auto storeH = [&](int buf) {
    #pragma unroll
    for (int i = 0; i < 4; ++i) {
      int idx = tid + i * BLK;
      int r = idx >> 4, c4 = idx & 15;
      ushort4 v;
      v.x = f2bf(hreg[i].x); v.y = f2bf(hreg[i].y);
      v.z = f2bf(hreg[i].z); v.w = f2bf(hreg[i].w);
      *(ushort4*)&hA[buf][r][c4 * 4] = v;
    }
  };
  auto storeW = [&](int buf) {
    #pragma unroll
    for (int i = 0; i < 3; ++i) {
      int idx = tid + i * BLK;
      int r = idx >> 4, c4 = idx & 15;
      ushort4 v;
      v.x = f2bf(wreg[i].x); v.y = f2bf(wreg[i].y);
      v.z = f2bf(wreg[i].z); v.w = f2bf(wreg[i].w);
      *(ushort4*)&wB[buf][r][c4 * 4] = v;
    }
  };

  f32x4 acc[3];
  #pragma unroll
  for (int nt = 0; nt < 3; ++nt) acc[nt] = f32x4{0.f, 0.f, 0.f, 0.f};

  auto compute = [&](int buf) {
    #pragma unroll
    for (int ks = 0; ks < 2; ++ks) {
      // A frag: row = wv*16 + (lane&15), k = ks*32 + quad*8 + j
      bf16x8 a = *(const bf16x8*)&hA[buf][(wv << 4) + mr][ks * 32 + (qd << 3)];
      #pragma unroll
      for (int nt = 0; nt < 3; ++nt) {
        bf16x8 bb = *(const bf16x8*)&wB[buf][(nt << 4) + mr][ks * 32 + (qd << 3)];
        acc[nt] = __builtin_amdgcn_mfma_f32_16x16x32_bf16(a, bb, acc[nt], 0, 0, 0);
      }
    }
  };

  // prologue
  loadH(0); loadW(0);
  storeH(0); storeW(0);
  __syncthreads();

  for (int c = 0; c < NCHUNK; ++c) {
    int cur = c & 1;
    if (c + 1 < NCHUNK) { loadH(c + 1); loadW(c + 1); }   // issue global loads early
    compute(cur);
    if (c + 1 < NCHUNK) { storeH(cur ^ 1); storeW(cur ^ 1); }
    __syncthreads();
  }

  // epilogue: C/D layout col = lane&15, row = quad*4 + reg
  int mrow[4];
  #pragma unroll
  for (int i = 0; i < 4; ++i)
    mrow[i] = mask[row0 + (wv << 4) + (qd << 2) + i];

  #pragma unroll
  for (int nt = 0; nt < 3; ++nt) {
    int p = (nt << 4) + mr;
    if (p < P2) {
      float bv = bias[p];
      float qv = q[b * P2 + p];
      #pragma unroll
      for (int i = 0; i < 4; ++i) {
        int row = row0 + (wv << 4) + (qd << 2) + i;
        float x = acc[nt][i] + bv + (mrow[i] ? qv : 0.f);
        float sg = 1.f / (1.f + __expf(-x));
        sg *= sg; sg *= sg;               // sigmoid^4
        out[(size_t)row * P2 + p] = sg;
      }
    }
  }
}

extern "C" void kernel_launch(void* const* d_in, const int* in_sizes, int n_in,
                              void* d_out, int out_size, void* d_ws, size_t ws_size,
                              hipStream_t stream) {
  const float* h    = (const float*)d_in[0];   // [64,512,768] fp32
  const int*   ids  = (const int*)d_in[1];     // [64,2]
  const int*   mask = (const int*)d_in[2];     // [64,512]
  const float* W    = (const float*)d_in[3];   // [46,768]
  const float* bias = (const float*)d_in[4];   // [46]
  float* out = (float*)d_out;                  // [64,512,46] fp32
  float* q   = (float*)d_ws;                   // [64,46] fp32 scratch

  qk_kernel<<<dim3(64, P2), 64, 0, stream>>>(h, ids, W, q);
  gemm_kernel<<<dim3((64 * SEQ) / MT), BLK, 0, stream>>>(h, mask, W, bias, q, out);
}